// Round 6
// baseline (161.046 us; speedup 1.0000x reference)
//
#include <hip/hip_runtime.h>
#include <hip/hip_bf16.h>
#include <math.h>

// B=2, T=2048, D=1024, H=16, hd=64, ALPHA=1 (decay = -(i-j))
// Pipeline: fused cast f32->bf16
//  -> QKV counted-vmcnt pipelined NT GEMM over stacked W [3072x1024]:
//     256x256 tile, BK=64, 8 waves, 128 KB LDS dbuf-by-K-tile, 4 phases/K-tile
//     (pm-half x kk-half), band-granular staging (64 rows = 1 load/thread)
//     into the dead buffer, vmcnt(2)/vmcnt(4) counted waits (never 0 in
//     steady state), setprio around MFMA clusters. Grid 192 = 1 block/CU.
//  -> windowed flash attn (j-tiles {qb-1,qb}; decay kills distance>64)
//  -> out NT GEMM (128x128 dbuf).
// NOTE: ~86us of dur_us is two 268MB harness poison-fills (43us each);
// controllable kernel budget ~62us; qkv ~40us (2-phase ceiling) before this.

typedef __bf16 bf16_t;
typedef bf16_t bf16x8 __attribute__((ext_vector_type(8)));
typedef bf16_t bf16x4 __attribute__((ext_vector_type(4)));
typedef float  floatx4 __attribute__((ext_vector_type(4)));

#define LOG2E 1.44269504088896f

#if __has_builtin(__builtin_amdgcn_exp2f)
#define EXP2(x) __builtin_amdgcn_exp2f(x)
#else
#define EXP2(x) exp2f(x)
#endif

__device__ __forceinline__ void async16(const bf16_t* g, bf16_t* l) {
  __builtin_amdgcn_global_load_lds(
      (const __attribute__((address_space(1))) unsigned int*)g,
      (__attribute__((address_space(3))) unsigned int*)l, 16, 0, 0);
}

// pack two f32 into bf16x2 by truncation (1 v_perm_b32); P>=0 -> rel err <= 2^-8
__device__ __forceinline__ unsigned pack_bf16_trunc(float lo, float hi) {
  return __builtin_amdgcn_perm(__builtin_bit_cast(unsigned, hi),
                               __builtin_bit_cast(unsigned, lo), 0x07060302u);
}

// ---------------- fused cast kernel ----------------
__global__ void castall(const float* __restrict__ x,
                        const float* __restrict__ wq, const float* __restrict__ wk,
                        const float* __restrict__ wv, const float* __restrict__ wo,
                        bf16_t* __restrict__ xb, bf16_t* __restrict__ wdst) {
  int i = blockIdx.x * blockDim.x + threadIdx.x;  // 0 .. 2097151
  const float* src;
  bf16_t* dst;
  if (i < 1048576) {
    src = x + (size_t)i * 4;
    dst = xb + (size_t)i * 4;
  } else {
    int i2 = i - 1048576;
    int wsel = i2 >> 18;
    int off = i2 & 262143;
    const float* wsrc = (wsel == 0) ? wq : (wsel == 1) ? wk : (wsel == 2) ? wv : wo;
    src = wsrc + (size_t)off * 4;
    dst = wdst + (size_t)i2 * 4;
  }
  const float4 f = *(const float4*)src;
  bf16x4 o;
  o[0] = (bf16_t)f.x; o[1] = (bf16_t)f.y; o[2] = (bf16_t)f.z; o[3] = (bf16_t)f.w;
  *(bf16x4*)dst = o;
}

// ---------------- QKV pipelined NT GEMM: C[4096x3072] = A[4096x1024].Wst^T ----------------
// Liveness-derived schedule. K-tile T computes from buf cur; all stages write
// buf nxt (holding T-1, fully consumed) -> no intra-tile LDS hazards.
// Per-phase reads (8 x ds_read_b128): phase (pm,kk) reads A rows
// [wm+pm*64,+64) x K-half kk and all 4 B col-frags x K-half kk.
// Band need-by-next-tile: {A0,A2,B0..B3} at phase 0, {A1,A3} at phase 2.
// Issue order: ph0: A0,A2 | ph1: B0,B1 | ph2: B2,B3 | ph3: A1,A3.
// Waits: ph0 vmcnt(2) [A1,A3 of cur still in flight], ph2 vmcnt(4)
// [A1,A3 of NEXT + B2,B3... = newest 4 in flight]. Never 0 until drain.
#define BK 64

#define QKV_RD(pm, kk)                                               \
  {                                                                  \
    _Pragma("unroll")                                                \
    for (int i = 0; i < 4; ++i) {                                    \
      int ra = wm + (pm) * 64 + i * 16 + l15;                        \
      int ps = ((kk) * 4 + q4) ^ (ra & 7);                           \
      af[i] = *(const bf16x8*)&As[cur][(ra * 8 + ps) * 8];           \
    }                                                                \
    _Pragma("unroll")                                                \
    for (int j = 0; j < 4; ++j) {                                    \
      int rb = wn + j * 16 + l15;                                    \
      int ps = ((kk) * 4 + q4) ^ (rb & 7);                           \
      bfv[j] = *(const bf16x8*)&Bs[cur][(rb * 8 + ps) * 8];          \
    }                                                                \
  }

#define QKV_MM(pm)                                                   \
  __builtin_amdgcn_s_setprio(1);                                     \
  _Pragma("unroll")                                                  \
  for (int i = 0; i < 4; ++i)                                        \
    _Pragma("unroll")                                                \
    for (int j = 0; j < 4; ++j)                                      \
      acc[(pm) * 4 + i][j] = __builtin_amdgcn_mfma_f32_16x16x32_bf16(\
          af[i], bfv[j], acc[(pm) * 4 + i][j], 0, 0, 0);             \
  __builtin_amdgcn_s_setprio(0);

#define LGKM0                                                        \
  asm volatile("s_waitcnt lgkmcnt(0)" ::: "memory");                 \
  __builtin_amdgcn_sched_barrier(0);

__global__ __launch_bounds__(512, 1)
void gemm_qkv(const bf16_t* __restrict__ A, const bf16_t* __restrict__ Wst,
              const float* __restrict__ b0, const float* __restrict__ b1,
              const float* __restrict__ b2,
              bf16_t* __restrict__ O0, bf16_t* __restrict__ O1,
              bf16_t* __restrict__ O2)
{
  __shared__ __align__(16) bf16_t As[2][256 * BK];   // 64 KB
  __shared__ __align__(16) bf16_t Bs[2][256 * BK];   // 64 KB
  const int t = threadIdx.x, w = t >> 6, lane = t & 63;
  const int l15 = lane & 15, q4 = lane >> 4;
  // XCD-bijective swizzle (192 = 8 * 24)
  const int orig = blockIdx.x;
  const int wgid = (orig & 7) * 24 + (orig >> 3);
  const int mb = wgid / 12, nb = wgid % 12;          // 16 m x 12 n
  const int m0 = mb * 256, n0 = nb * 256;
  const int wm = (w >> 2) * 128, wn = (w & 3) * 64;  // 2M x 4N waves, 128x64/wave

  floatx4 acc[8][4];
#pragma unroll
  for (int i = 0; i < 8; ++i)
#pragma unroll
    for (int j = 0; j < 4; ++j) acc[i][j] = (floatx4){0.f, 0.f, 0.f, 0.f};
  bf16x8 af[4], bfv[4];

  // band stage: 64 rows = 512 chunks = 1 load/thread; LDS linear in t;
  // global seg pre-XOR-swizzled: g = (t&7) ^ ((t>>3)&7)
  const int srow = t >> 3;
  const int sg = (t & 7) ^ (srow & 7);
  auto stA = [&](int buf, int k0, int band) {
    async16(A + (size_t)(m0 + band * 64 + srow) * 1024 + k0 + sg * 8,
            &As[buf][(band * 512 + t) * 8]);
  };
  auto stB = [&](int buf, int k0, int band) {
    async16(Wst + (size_t)(n0 + band * 64 + srow) * 1024 + k0 + sg * 8,
            &Bs[buf][(band * 512 + t) * 8]);
  };

  // prologue: stage K-tile 0 into buf 0 in need-order; loop waits handle it
  stA(0, 0, 0); stA(0, 0, 2);
  stB(0, 0, 0); stB(0, 0, 1); stB(0, 0, 2); stB(0, 0, 3);
  stA(0, 0, 1); stA(0, 0, 3);

  for (int kt = 0; kt < 16; ++kt) {
    const int cur = kt & 1, nxt = cur ^ 1;
    const int k1 = (kt + 1) << 6;
    const bool pf = kt < 15;

    // ---- phase 0: pm=0, kk=0 ----
    asm volatile("s_waitcnt vmcnt(2)" ::: "memory");   // A0,A2,B0-3 of cur landed
    __builtin_amdgcn_s_barrier();
    __builtin_amdgcn_sched_barrier(0);
    QKV_RD(0, 0);
    if (pf) { stA(nxt, k1, 0); stA(nxt, k1, 2); }
    LGKM0;
    QKV_MM(0);

    // ---- phase 1: pm=0, kk=1 ----
    __builtin_amdgcn_s_barrier();
    QKV_RD(0, 1);
    if (pf) { stB(nxt, k1, 0); stB(nxt, k1, 1); }
    LGKM0;
    QKV_MM(0);

    // ---- phase 2: pm=1, kk=0 ----
    if (pf) { asm volatile("s_waitcnt vmcnt(4)" ::: "memory"); }  // A1,A3 of cur landed
    else    { asm volatile("s_waitcnt vmcnt(0)" ::: "memory"); }
    __builtin_amdgcn_s_barrier();
    __builtin_amdgcn_sched_barrier(0);
    QKV_RD(1, 0);
    if (pf) { stB(nxt, k1, 2); stB(nxt, k1, 3); }
    LGKM0;
    QKV_MM(1);

    // ---- phase 3: pm=1, kk=1 ----
    __builtin_amdgcn_s_barrier();
    QKV_RD(1, 1);
    if (pf) { stA(nxt, k1, 1); stA(nxt, k1, 3); }
    LGKM0;
    QKV_MM(1);
  }

  // epilogue; C/D layout: col = lane&15, row = (lane>>4)*4 + reg.
  // 16-col fragments never straddle a 1024-col matrix boundary.
#pragma unroll
  for (int i = 0; i < 8; ++i) {
    const int rowg = m0 + wm + i * 16 + q4 * 4;
#pragma unroll
    for (int j = 0; j < 4; ++j) {
      const int col = n0 + wn + j * 16 + l15;
      const int cmat = col >> 10, lcol = col & 1023;
      const float* bp = (cmat == 0) ? b0 : (cmat == 1) ? b1 : b2;
      const float bv = bp[lcol];
      if (cmat == 2) {
        // V transposed: Vt[b][d][t]; lane holds 4 consecutive t -> 8B store
        int bb = rowg >> 11, tt = rowg & 2047;
        bf16x4 pk;
#pragma unroll
        for (int r = 0; r < 4; ++r) pk[r] = (bf16_t)(acc[i][j][r] + bv);
        *(bf16x4*)(O2 + (size_t)(bb * 1024 + lcol) * 2048 + tt) = pk;
      } else {
        bf16_t* Om = cmat ? O1 : O0;
#pragma unroll
        for (int r = 0; r < 4; ++r)
          Om[(size_t)(rowg + r) * 1024 + lcol] = (bf16_t)(acc[i][j][r] + bv);
      }
    }
  }
}

// ---------------- out NT GEMM: 128x128 tile, dbuf, 2 blocks/CU (f32 out) ----------------
__global__ __launch_bounds__(512, 2)
void gemm_out(const bf16_t* __restrict__ A, const bf16_t* __restrict__ Wm,
              const float* __restrict__ bias, float* __restrict__ OF)
{
  __shared__ __align__(16) bf16_t As[2][128 * BK];   // 32 KB
  __shared__ __align__(16) bf16_t Bs[2][128 * BK];   // 32 KB
  const int t = threadIdx.x, w = t >> 6, lane = t & 63;
  const int l15 = lane & 15, q4 = lane >> 4;
  const int orig = blockIdx.x;
  const int wgid = (orig & 7) * 32 + (orig >> 3);    // XCD-bijective swizzle
  const int mb = wgid >> 3, nbk = wgid & 7;          // 32 m x 8 n
  const int m0 = mb * 128, n0 = nbk * 128;
  const int wm = (w >> 2) * 64, wn = (w & 3) * 32;   // 2x4 wave grid over 128x128

  floatx4 acc[4][2];
#pragma unroll
  for (int mi = 0; mi < 4; ++mi)
#pragma unroll
    for (int ni = 0; ni < 2; ++ni) acc[mi][ni] = (floatx4){0.f, 0.f, 0.f, 0.f};

  auto stage = [&](int buf, int k0) {
#pragma unroll
    for (int c = 0; c < 2; ++c) {
      int chunk = t + c * 512;                 // 0..1023
      int row = chunk >> 3;
      int g = (chunk & 7) ^ (row & 7);
      async16(A  + (size_t)(m0 + row) * 1024 + k0 + g * 8, &As[buf][chunk * 8]);
      async16(Wm + (size_t)(n0 + row) * 1024 + k0 + g * 8, &Bs[buf][chunk * 8]);
    }
  };

  stage(0, 0);
  __syncthreads();
  for (int it = 0; it < 16; ++it) {
    const int cur = it & 1;
    if (it + 1 < 16) stage(cur ^ 1, (it + 1) * BK);

#pragma unroll
    for (int kk = 0; kk < 2; ++kk) {
      bf16x8 af[4], bfr[2];
#pragma unroll
      for (int i = 0; i < 4; ++i) {
        int ra = wm + i * 16 + l15;
        int pa = (kk * 4 + q4) ^ (ra & 7);
        af[i] = *(const bf16x8*)&As[cur][ra * BK + pa * 8];
      }
#pragma unroll
      for (int i = 0; i < 2; ++i) {
        int rb = wn + i * 16 + l15;
        int pb = (kk * 4 + q4) ^ (rb & 7);
        bfr[i] = *(const bf16x8*)&Bs[cur][rb * BK + pb * 8];
      }
#pragma unroll
      for (int mi = 0; mi < 4; ++mi)
#pragma unroll
        for (int ni = 0; ni < 2; ++ni)
          acc[mi][ni] = __builtin_amdgcn_mfma_f32_16x16x32_bf16(
              af[mi], bfr[ni], acc[mi][ni], 0, 0, 0);
    }
    __syncthreads();
  }

#pragma unroll
  for (int mi = 0; mi < 4; ++mi)
#pragma unroll
    for (int ni = 0; ni < 2; ++ni) {
      const int col = n0 + wn + ni * 16 + l15;
      const float bv = bias[col];
#pragma unroll
      for (int r = 0; r < 4; ++r) {
        int row = m0 + wm + mi * 16 + q4 * 4 + r;
        OF[(size_t)row * 1024 + col] = acc[mi][ni][r] + bv;
      }
    }
}

// ---------------- windowed flash attention: j-tiles {qb-1, qb} only ----------------
// decay e^{-(i-j)} makes keys at distance >64 weigh < e^{-58}: below f32 ulp.
__global__ __launch_bounds__(256, 3)
void attn_kernel(const bf16_t* __restrict__ Qb, const bf16_t* __restrict__ Kb,
                 const bf16_t* __restrict__ Vt, bf16_t* __restrict__ AO)
{
  __shared__ __align__(16) bf16_t Ks[2][64 * 64];
  __shared__ __align__(16) bf16_t Vs[2][64 * 64];
  __shared__ __align__(16) bf16_t Ps[4][16][72];

  const int t = threadIdx.x, w = t >> 6, lane = t & 63;
  const int l15 = lane & 15, q4 = lane >> 4;
  const int bh = blockIdx.x & 31, qb = blockIdx.x >> 5;
  const int b = bh >> 4, h = bh & 15;
  const int i0 = qb * 64;
  const int jstart = (qb > 0) ? (qb - 1) : 0;
  const int nIter = qb - jstart + 1;      // 1 (qb==0) or 2

  const float C1 = 0.125f * LOG2E;        // (1/sqrt(64)) * log2e
  const float CL = LOG2E;
  const float Er[4] = {1.0f, 2.71828182846f, 7.38905609893f, 20.0855369232f};

  const bf16_t* qp = Qb + ((size_t)(b * 2048 + i0 + w * 16 + l15)) * 1024 + h * 64 + q4 * 8;
  const bf16x8 qf0 = *(const bf16x8*)qp;
  const bf16x8 qf1 = *(const bf16x8*)(qp + 32);

  floatx4 o_acc[4], lsum;
  lsum = (floatx4){0.f, 0.f, 0.f, 0.f};
#pragma unroll
  for (int dt = 0; dt < 4; ++dt) o_acc[dt] = (floatx4){0.f, 0.f, 0.f, 0.f};
  bf16x8 ones;
#pragma unroll
  for (int e = 0; e < 8; ++e) ones[e] = (bf16_t)1.0f;

  float dm[4];
#pragma unroll
  for (int mt = 0; mt < 4; ++mt)
    dm[mt] = (float)(jstart * 64 + mt * 16 + q4 * 4 - w * 16 - l15 - i0) * CL;
  const int relMask = w * 16 + l15;

  const int chA = w * 128 + lane, chB = chA + 64;
  const int rA = chA >> 3, rB = chB >> 3;
  const int sA = (chA & 7) ^ (rA & 7), sB = (chB & 7) ^ (rB & 7);
  const bf16_t* kpA = Kb + ((size_t)(b * 2048 + jstart * 64 + rA)) * 1024 + h * 64 + sA * 8;
  const bf16_t* kpB = Kb + ((size_t)(b * 2048 + jstart * 64 + rB)) * 1024 + h * 64 + sB * 8;
  const bf16_t* vpA = Vt + ((size_t)(b * 1024 + h * 64 + rA)) * 2048 + jstart * 64 + sA * 8;
  const bf16_t* vpB = Vt + ((size_t)(b * 1024 + h * 64 + rB)) * 2048 + jstart * 64 + sB * 8;

  auto stage = [&](int buf) {
    async16(kpA, &Ks[buf][chA * 8]);
    async16(kpB, &Ks[buf][chB * 8]);
    async16(vpA, &Vs[buf][chA * 8]);
    async16(vpB, &Vs[buf][chB * 8]);
    kpA += 65536; kpB += 65536;
    vpA += 64;    vpB += 64;
  };

  stage(0);
  for (int it = 0; it < nIter; ++it) {
    __syncthreads();
    if (it + 1 < nIter) stage(1);
    const int cur = it;

    const bool diag = (it == nIter - 1);
#pragma unroll
    for (int mt = 0; mt < 4; ++mt) {
      int row = mt * 16 + l15;
      int s0 = q4 ^ (row & 7);
      int s1 = (4 + q4) ^ (row & 7);
      bf16x8 kf0 = *(const bf16x8*)&Ks[cur][row * 64 + s0 * 8];
      bf16x8 kf1 = *(const bf16x8*)&Ks[cur][row * 64 + s1 * 8];
      floatx4 s4 = __builtin_amdgcn_mfma_f32_16x16x32_bf16(kf0, qf0,
                       (floatx4){0.f, 0.f, 0.f, 0.f}, 0, 0, 0);
      s4 = __builtin_amdgcn_mfma_f32_16x16x32_bf16(kf1, qf1, s4, 0, 0, 0);

      float p[4];
#pragma unroll
      for (int r = 0; r < 4; ++r) {
        float v = EXP2(fmaf(s4[r], C1, dm[mt])) * Er[r];
        if (diag && (mt * 16 + q4 * 4 + r) > relMask) v = 0.f;
        p[r] = v;
      }
      uint2 pk2;
      pk2.x = pack_bf16_trunc(p[0], p[1]);
      pk2.y = pack_bf16_trunc(p[2], p[3]);
      *(uint2*)&Ps[w][l15][mt * 16 + q4 * 4] = pk2;
      dm[mt] += 64.0f * CL;
    }

    __builtin_amdgcn_s_waitcnt(0xC07F);  // lgkmcnt(0): own-wave P writes visible

    bf16x8 pf0 = *(const bf16x8*)&Ps[w][l15][q4 * 8];
    bf16x8 pf1 = *(const bf16x8*)&Ps[w][l15][32 + q4 * 8];
    lsum = __builtin_amdgcn_mfma_f32_16x16x32_bf16(pf0, ones, lsum, 0, 0, 0);
    lsum = __builtin_amdgcn_mfma_f32_16x16x32_bf16(pf1, ones, lsum, 0, 0, 0);
#pragma unroll
    for (int dt = 0; dt < 4; ++dt) {
      int row = dt * 16 + l15;
      int s0 = q4 ^ (row & 7);
      int s1 = (4 + q4) ^ (row & 7);
      bf16x8 vf0 = *(const bf16x8*)&Vs[cur][row * 64 + s0 * 8];
      bf16x8 vf1 = *(const bf16x8*)&Vs[cur][row * 64 + s1 * 8];
      o_acc[dt] = __builtin_amdgcn_mfma_f32_16x16x32_bf16(pf0, vf0, o_acc[dt], 0, 0, 0);
      o_acc[dt] = __builtin_amdgcn_mfma_f32_16x16x32_bf16(pf1, vf1, o_acc[dt], 0, 0, 0);
    }
  }

  floatx4 inv;
#pragma unroll
  for (int r = 0; r < 4; ++r) inv[r] = 1.0f / lsum[r];
#pragma unroll
  for (int dt = 0; dt < 4; ++dt)
#pragma unroll
    for (int r = 0; r < 4; ++r) {
      int i = i0 + w * 16 + q4 * 4 + r;
      AO[((size_t)(b * 2048 + i)) * 1024 + h * 64 + dt * 16 + l15] =
          (bf16_t)(o_acc[dt][r] * inv[r]);
    }
}

// ---------------- launch ----------------
extern "C" void kernel_launch(void* const* d_in, const int* in_sizes, int n_in,
                              void* d_out, int out_size, void* d_ws, size_t ws_size,
                              hipStream_t stream) {
  const float* x  = (const float*)d_in[0];
  const float* Wq = (const float*)d_in[1];
  const float* bq = (const float*)d_in[2];
  const float* Wk = (const float*)d_in[3];
  const float* bk = (const float*)d_in[4];
  const float* Wv = (const float*)d_in[5];
  const float* bv = (const float*)d_in[6];
  const float* Wo = (const float*)d_in[7];
  const float* bo = (const float*)d_in[8];

  char* ws = (char*)d_ws;                      // needs >= 48 MB
  bf16_t* xb  = (bf16_t*)(ws);                 //  8 MB
  bf16_t* wqb = (bf16_t*)(ws + (8u  << 20));   //  2 MB (wq,wk,wv,wo contiguous)
  bf16_t* wob = (bf16_t*)(ws + (14u << 20));
  bf16_t* Qb  = (bf16_t*)(ws + (16u << 20));   //  8 MB  [b,t,h,d]
  bf16_t* Kb  = (bf16_t*)(ws + (24u << 20));   //  8 MB  [b,t,h,d]
  bf16_t* Vtb = (bf16_t*)(ws + (32u << 20));   //  8 MB  [b,h*d,t]
  bf16_t* AOb = (bf16_t*)(ws + (40u << 20));   //  8 MB  [b,t,h,d]

  castall<<<8192, 256, 0, stream>>>(x, Wq, Wk, Wv, Wo, xb, wqb);

  // QKV over stacked W [3072x1024]: 192 blocks (16m x 12n), 512 thr, 1/CU
  gemm_qkv<<<192, 512, 0, stream>>>(
      xb, wqb, bq, bk, bv, Qb, Kb, Vtb);

  attn_kernel<<<1024, 256, 0, stream>>>(Qb, Kb, Vtb, AOb);

  // out: 256 blocks (32 m x 8 n) x 512 threads, dbuf, 2 blocks/CU
  gemm_out<<<256, 512, 0, stream>>>(AOb, wob, bo, (float*)d_out);
}

// Round 8
// 148.553 us; speedup vs baseline: 1.0841x; 1.0841x over previous
//
#include <hip/hip_runtime.h>
#include <hip/hip_bf16.h>
#include <math.h>

// B=2, T=2048, D=1024, H=16, hd=64, ALPHA=1 (decay = -(i-j))
// Pipeline: fused cast f32->bf16
//  -> QKV counted-vmcnt pipelined NT GEMM over stacked W [3072x1024]:
//     256x192 tile -> grid 16x16 = 256 blocks = 1/CU, ZERO idle CUs (r6's
//     192-block grid idled 25% of the chip). BK=64, 8 waves (2Mx4N, 128x48
//     per wave), 112 KB LDS dbuf-by-K-tile, 4 phases/K-tile, band staging
//     (64 rows = 1 load/thread) into the dead buffer, counted waits
//     vmcnt(2)/vmcnt(5) (never 0 in steady state), setprio on MFMA clusters.
//  -> windowed flash attn (j-tiles {qb-1,qb}; decay kills distance>64)
//  -> out NT GEMM (128x128 dbuf).
// NOTE: ~86us of dur_us is two 268MB harness poison-fills (43us each);
// controllable kernel budget ~62us; qkv best so far 40us (2-phase r4).
// (r7 bench was an infra failure -- container died twice; same source
// resubmitted after hang-audit: barriers uniform, vmcnt counts verified,
// no LDS write/read hazard across the ph0 barrier.)

typedef __bf16 bf16_t;
typedef bf16_t bf16x8 __attribute__((ext_vector_type(8)));
typedef bf16_t bf16x4 __attribute__((ext_vector_type(4)));
typedef float  floatx4 __attribute__((ext_vector_type(4)));

#define LOG2E 1.44269504088896f

#if __has_builtin(__builtin_amdgcn_exp2f)
#define EXP2(x) __builtin_amdgcn_exp2f(x)
#else
#define EXP2(x) exp2f(x)
#endif

__device__ __forceinline__ void async16(const bf16_t* g, bf16_t* l) {
  __builtin_amdgcn_global_load_lds(
      (const __attribute__((address_space(1))) unsigned int*)g,
      (__attribute__((address_space(3))) unsigned int*)l, 16, 0, 0);
}

// pack two f32 into bf16x2 by truncation (1 v_perm_b32); P>=0 -> rel err <= 2^-8
__device__ __forceinline__ unsigned pack_bf16_trunc(float lo, float hi) {
  return __builtin_amdgcn_perm(__builtin_bit_cast(unsigned, hi),
                               __builtin_bit_cast(unsigned, lo), 0x07060302u);
}

// ---------------- fused cast kernel ----------------
__global__ void castall(const float* __restrict__ x,
                        const float* __restrict__ wq, const float* __restrict__ wk,
                        const float* __restrict__ wv, const float* __restrict__ wo,
                        bf16_t* __restrict__ xb, bf16_t* __restrict__ wdst) {
  int i = blockIdx.x * blockDim.x + threadIdx.x;  // 0 .. 2097151
  const float* src;
  bf16_t* dst;
  if (i < 1048576) {
    src = x + (size_t)i * 4;
    dst = xb + (size_t)i * 4;
  } else {
    int i2 = i - 1048576;
    int wsel = i2 >> 18;
    int off = i2 & 262143;
    const float* wsrc = (wsel == 0) ? wq : (wsel == 1) ? wk : (wsel == 2) ? wv : wo;
    src = wsrc + (size_t)off * 4;
    dst = wdst + (size_t)i2 * 4;
  }
  const float4 f = *(const float4*)src;
  bf16x4 o;
  o[0] = (bf16_t)f.x; o[1] = (bf16_t)f.y; o[2] = (bf16_t)f.z; o[3] = (bf16_t)f.w;
  *(bf16x4*)dst = o;
}

// ---------------- QKV pipelined NT GEMM: C[4096x3072] = A[4096x1024].Wst^T ----------------
// Liveness-derived schedule. K-tile T computes from buf cur; stages write buf
// nxt (holding T-1, fully consumed) -> no intra-tile LDS hazards.
// Phase (pm,kk): waves 0-3 read A rows [pm*64,+64), waves 4-7 [128+pm*64,+64)
// -> ph0/1 consume A-bands {0,2}, ph2/3 consume {1,3}; all phases read B.
// Band issue: ph0: A0,A2,B0 | ph1: B1,B2 | ph2: A1,A3 (7 loads/thread).
// Waits: ph0 vmcnt(2) [A1,A3 of cur still fly], ph2 vmcnt(5) [5 next-tile
// bands fly]. vmcnt(0) only at last-tile ph2.
#define BK 64

#define QKV_RD(pm, kk)                                               \
  {                                                                  \
    _Pragma("unroll")                                                \
    for (int i = 0; i < 4; ++i) {                                    \
      int ra = wm + (pm) * 64 + i * 16 + l15;                        \
      int ps = ((kk) * 4 + q4) ^ (ra & 7);                           \
      af[i] = *(const bf16x8*)&As[cur][(ra * 8 + ps) * 8];           \
    }                                                                \
    _Pragma("unroll")                                                \
    for (int j = 0; j < 3; ++j) {                                    \
      int rb = wn + j * 16 + l15;                                    \
      int ps = ((kk) * 4 + q4) ^ (rb & 7);                           \
      bfv[j] = *(const bf16x8*)&Bs[cur][(rb * 8 + ps) * 8];          \
    }                                                                \
  }

#define QKV_MM(pm)                                                   \
  __builtin_amdgcn_s_setprio(1);                                     \
  _Pragma("unroll")                                                  \
  for (int i = 0; i < 4; ++i)                                        \
    _Pragma("unroll")                                                \
    for (int j = 0; j < 3; ++j)                                      \
      acc[(pm) * 4 + i][j] = __builtin_amdgcn_mfma_f32_16x16x32_bf16(\
          af[i], bfv[j], acc[(pm) * 4 + i][j], 0, 0, 0);             \
  __builtin_amdgcn_s_setprio(0);

#define LGKM0                                                        \
  asm volatile("s_waitcnt lgkmcnt(0)" ::: "memory");                 \
  __builtin_amdgcn_sched_barrier(0);

__global__ __launch_bounds__(512, 1)
void gemm_qkv(const bf16_t* __restrict__ A, const bf16_t* __restrict__ Wst,
              const float* __restrict__ b0, const float* __restrict__ b1,
              const float* __restrict__ b2,
              bf16_t* __restrict__ O0, bf16_t* __restrict__ O1,
              bf16_t* __restrict__ O2)
{
  __shared__ __align__(16) bf16_t As[2][256 * BK];   // 64 KB
  __shared__ __align__(16) bf16_t Bs[2][192 * BK];   // 48 KB
  const int t = threadIdx.x, w = t >> 6, lane = t & 63;
  const int l15 = lane & 15, q4 = lane >> 4;
  // XCD-bijective swizzle (256 % 8 == 0)
  const int orig = blockIdx.x;
  const int wgid = (orig & 7) * 32 + (orig >> 3);
  const int mb = wgid >> 4, nb = wgid & 15;          // 16 m x 16 n
  const int m0 = mb * 256, n0 = nb * 192;
  const int wm = (w >> 2) * 128, wn = (w & 3) * 48;  // 2M x 4N waves, 128x48/wave

  floatx4 acc[8][3];
#pragma unroll
  for (int i = 0; i < 8; ++i)
#pragma unroll
    for (int j = 0; j < 3; ++j) acc[i][j] = (floatx4){0.f, 0.f, 0.f, 0.f};
  bf16x8 af[4], bfv[3];

  // band stage: 64 rows = 512 chunks = 1 load/thread; LDS linear in t;
  // global seg pre-XOR-swizzled: g = (t&7) ^ ((t>>3)&7)
  const int srow = t >> 3;
  const int sg = (t & 7) ^ (srow & 7);
  auto stA = [&](int buf, int k0, int band) {
    async16(A + (size_t)(m0 + band * 64 + srow) * 1024 + k0 + sg * 8,
            &As[buf][(band * 512 + t) * 8]);
  };
  auto stB = [&](int buf, int k0, int band) {
    async16(Wst + (size_t)(n0 + band * 64 + srow) * 1024 + k0 + sg * 8,
            &Bs[buf][(band * 512 + t) * 8]);
  };

  // prologue: stage K-tile 0 into buf 0 in need-order
  stA(0, 0, 0); stA(0, 0, 2); stB(0, 0, 0);
  stB(0, 0, 1); stB(0, 0, 2);
  stA(0, 0, 1); stA(0, 0, 3);

  for (int kt = 0; kt < 16; ++kt) {
    const int cur = kt & 1, nxt = cur ^ 1;
    const int k1 = (kt + 1) << 6;
    const bool pf = kt < 15;

    // ---- phase 0: pm=0, kk=0 ----
    asm volatile("s_waitcnt vmcnt(2)" ::: "memory");   // A0,A2,B0,B1,B2 of cur landed
    __builtin_amdgcn_s_barrier();
    __builtin_amdgcn_sched_barrier(0);
    QKV_RD(0, 0);
    if (pf) { stA(nxt, k1, 0); stA(nxt, k1, 2); stB(nxt, k1, 0); }
    LGKM0;
    QKV_MM(0);

    // ---- phase 1: pm=0, kk=1 ----
    __builtin_amdgcn_s_barrier();
    QKV_RD(0, 1);
    if (pf) { stB(nxt, k1, 1); stB(nxt, k1, 2); }
    LGKM0;
    QKV_MM(0);

    // ---- phase 2: pm=1, kk=0 ----
    if (pf) { asm volatile("s_waitcnt vmcnt(5)" ::: "memory"); }  // A1,A3 of cur landed
    else    { asm volatile("s_waitcnt vmcnt(0)" ::: "memory"); }
    __builtin_amdgcn_s_barrier();
    __builtin_amdgcn_sched_barrier(0);
    QKV_RD(1, 0);
    if (pf) { stA(nxt, k1, 1); stA(nxt, k1, 3); }
    LGKM0;
    QKV_MM(1);

    // ---- phase 3: pm=1, kk=1 ----
    __builtin_amdgcn_s_barrier();
    QKV_RD(1, 1);
    LGKM0;
    QKV_MM(1);
  }

  // epilogue; C/D layout: col = lane&15, row = (lane>>4)*4 + reg.
  // acc row i: global row = m0 + wm + i*16 (i>=4 lands in pm=1 half since
  // i*16 = 64 + (i-4)*16). 16-col fragments never straddle a matrix boundary.
#pragma unroll
  for (int i = 0; i < 8; ++i) {
    const int rowg = m0 + wm + i * 16 + q4 * 4;
#pragma unroll
    for (int j = 0; j < 3; ++j) {
      const int col = n0 + wn + j * 16 + l15;
      const int cmat = col >> 10, lcol = col & 1023;
      const float* bp = (cmat == 0) ? b0 : (cmat == 1) ? b1 : b2;
      const float bv = bp[lcol];
      if (cmat == 2) {
        // V transposed: Vt[b][d][t]; lane holds 4 consecutive t -> 8B store
        int bb = rowg >> 11, tt = rowg & 2047;
        bf16x4 pk;
#pragma unroll
        for (int r = 0; r < 4; ++r) pk[r] = (bf16_t)(acc[i][j][r] + bv);
        *(bf16x4*)(O2 + (size_t)(bb * 1024 + lcol) * 2048 + tt) = pk;
      } else {
        bf16_t* Om = cmat ? O1 : O0;
#pragma unroll
        for (int r = 0; r < 4; ++r)
          Om[(size_t)(rowg + r) * 1024 + lcol] = (bf16_t)(acc[i][j][r] + bv);
      }
    }
  }
}

// ---------------- out NT GEMM: 128x128 tile, dbuf, 2 blocks/CU (f32 out) ----------------
__global__ __launch_bounds__(512, 2)
void gemm_out(const bf16_t* __restrict__ A, const bf16_t* __restrict__ Wm,
              const float* __restrict__ bias, float* __restrict__ OF)
{
  __shared__ __align__(16) bf16_t As[2][128 * BK];   // 32 KB
  __shared__ __align__(16) bf16_t Bs[2][128 * BK];   // 32 KB
  const int t = threadIdx.x, w = t >> 6, lane = t & 63;
  const int l15 = lane & 15, q4 = lane >> 4;
  const int orig = blockIdx.x;
  const int wgid = (orig & 7) * 32 + (orig >> 3);    // XCD-bijective swizzle
  const int mb = wgid >> 3, nbk = wgid & 7;          // 32 m x 8 n
  const int m0 = mb * 128, n0 = nbk * 128;
  const int wm = (w >> 2) * 64, wn = (w & 3) * 32;   // 2x4 wave grid over 128x128

  floatx4 acc[4][2];
#pragma unroll
  for (int mi = 0; mi < 4; ++mi)
#pragma unroll
    for (int ni = 0; ni < 2; ++ni) acc[mi][ni] = (floatx4){0.f, 0.f, 0.f, 0.f};

  auto stage = [&](int buf, int k0) {
#pragma unroll
    for (int c = 0; c < 2; ++c) {
      int chunk = t + c * 512;                 // 0..1023
      int row = chunk >> 3;
      int g = (chunk & 7) ^ (row & 7);
      async16(A  + (size_t)(m0 + row) * 1024 + k0 + g * 8, &As[buf][chunk * 8]);
      async16(Wm + (size_t)(n0 + row) * 1024 + k0 + g * 8, &Bs[buf][chunk * 8]);
    }
  };

  stage(0, 0);
  __syncthreads();
  for (int it = 0; it < 16; ++it) {
    const int cur = it & 1;
    if (it + 1 < 16) stage(cur ^ 1, (it + 1) * BK);

#pragma unroll
    for (int kk = 0; kk < 2; ++kk) {
      bf16x8 af[4], bfr[2];
#pragma unroll
      for (int i = 0; i < 4; ++i) {
        int ra = wm + i * 16 + l15;
        int pa = (kk * 4 + q4) ^ (ra & 7);
        af[i] = *(const bf16x8*)&As[cur][ra * BK + pa * 8];
      }
#pragma unroll
      for (int i = 0; i < 2; ++i) {
        int rb = wn + i * 16 + l15;
        int pb = (kk * 4 + q4) ^ (rb & 7);
        bfr[i] = *(const bf16x8*)&Bs[cur][rb * BK + pb * 8];
      }
#pragma unroll
      for (int mi = 0; mi < 4; ++mi)
#pragma unroll
        for (int ni = 0; ni < 2; ++ni)
          acc[mi][ni] = __builtin_amdgcn_mfma_f32_16x16x32_bf16(
              af[mi], bfr[ni], acc[mi][ni], 0, 0, 0);
    }
    __syncthreads();
  }

#pragma unroll
  for (int mi = 0; mi < 4; ++mi)
#pragma unroll
    for (int ni = 0; ni < 2; ++ni) {
      const int col = n0 + wn + ni * 16 + l15;
      const float bv = bias[col];
#pragma unroll
      for (int r = 0; r < 4; ++r) {
        int row = m0 + wm + mi * 16 + q4 * 4 + r;
        OF[(size_t)row * 1024 + col] = acc[mi][ni][r] + bv;
      }
    }
}

// ---------------- windowed flash attention: j-tiles {qb-1, qb} only ----------------
// decay e^{-(i-j)} makes keys at distance >64 weigh < e^{-58}: below f32 ulp.
__global__ __launch_bounds__(256, 3)
void attn_kernel(const bf16_t* __restrict__ Qb, const bf16_t* __restrict__ Kb,
                 const bf16_t* __restrict__ Vt, bf16_t* __restrict__ AO)
{
  __shared__ __align__(16) bf16_t Ks[2][64 * 64];
  __shared__ __align__(16) bf16_t Vs[2][64 * 64];
  __shared__ __align__(16) bf16_t Ps[4][16][72];

  const int t = threadIdx.x, w = t >> 6, lane = t & 63;
  const int l15 = lane & 15, q4 = lane >> 4;
  const int bh = blockIdx.x & 31, qb = blockIdx.x >> 5;
  const int b = bh >> 4, h = bh & 15;
  const int i0 = qb * 64;
  const int jstart = (qb > 0) ? (qb - 1) : 0;
  const int nIter = qb - jstart + 1;      // 1 (qb==0) or 2

  const float C1 = 0.125f * LOG2E;        // (1/sqrt(64)) * log2e
  const float CL = LOG2E;
  const float Er[4] = {1.0f, 2.71828182846f, 7.38905609893f, 20.0855369232f};

  const bf16_t* qp = Qb + ((size_t)(b * 2048 + i0 + w * 16 + l15)) * 1024 + h * 64 + q4 * 8;
  const bf16x8 qf0 = *(const bf16x8*)qp;
  const bf16x8 qf1 = *(const bf16x8*)(qp + 32);

  floatx4 o_acc[4], lsum;
  lsum = (floatx4){0.f, 0.f, 0.f, 0.f};
#pragma unroll
  for (int dt = 0; dt < 4; ++dt) o_acc[dt] = (floatx4){0.f, 0.f, 0.f, 0.f};
  bf16x8 ones;
#pragma unroll
  for (int e = 0; e < 8; ++e) ones[e] = (bf16_t)1.0f;

  float dm[4];
#pragma unroll
  for (int mt = 0; mt < 4; ++mt)
    dm[mt] = (float)(jstart * 64 + mt * 16 + q4 * 4 - w * 16 - l15 - i0) * CL;
  const int relMask = w * 16 + l15;

  const int chA = w * 128 + lane, chB = chA + 64;
  const int rA = chA >> 3, rB = chB >> 3;
  const int sA = (chA & 7) ^ (rA & 7), sB = (chB & 7) ^ (rB & 7);
  const bf16_t* kpA = Kb + ((size_t)(b * 2048 + jstart * 64 + rA)) * 1024 + h * 64 + sA * 8;
  const bf16_t* kpB = Kb + ((size_t)(b * 2048 + jstart * 64 + rB)) * 1024 + h * 64 + sB * 8;
  const bf16_t* vpA = Vt + ((size_t)(b * 1024 + h * 64 + rA)) * 2048 + jstart * 64 + sA * 8;
  const bf16_t* vpB = Vt + ((size_t)(b * 1024 + h * 64 + rB)) * 2048 + jstart * 64 + sB * 8;

  auto stage = [&](int buf) {
    async16(kpA, &Ks[buf][chA * 8]);
    async16(kpB, &Ks[buf][chB * 8]);
    async16(vpA, &Vs[buf][chA * 8]);
    async16(vpB, &Vs[buf][chB * 8]);
    kpA += 65536; kpB += 65536;
    vpA += 64;    vpB += 64;
  };

  stage(0);
  for (int it = 0; it < nIter; ++it) {
    __syncthreads();
    if (it + 1 < nIter) stage(1);
    const int cur = it;

    const bool diag = (it == nIter - 1);
#pragma unroll
    for (int mt = 0; mt < 4; ++mt) {
      int row = mt * 16 + l15;
      int s0 = q4 ^ (row & 7);
      int s1 = (4 + q4) ^ (row & 7);
      bf16x8 kf0 = *(const bf16x8*)&Ks[cur][row * 64 + s0 * 8];
      bf16x8 kf1 = *(const bf16x8*)&Ks[cur][row * 64 + s1 * 8];
      floatx4 s4 = __builtin_amdgcn_mfma_f32_16x16x32_bf16(kf0, qf0,
                       (floatx4){0.f, 0.f, 0.f, 0.f}, 0, 0, 0);
      s4 = __builtin_amdgcn_mfma_f32_16x16x32_bf16(kf1, qf1, s4, 0, 0, 0);

      float p[4];
#pragma unroll
      for (int r = 0; r < 4; ++r) {
        float v = EXP2(fmaf(s4[r], C1, dm[mt])) * Er[r];
        if (diag && (mt * 16 + q4 * 4 + r) > relMask) v = 0.f;
        p[r] = v;
      }
      uint2 pk2;
      pk2.x = pack_bf16_trunc(p[0], p[1]);
      pk2.y = pack_bf16_trunc(p[2], p[3]);
      *(uint2*)&Ps[w][l15][mt * 16 + q4 * 4] = pk2;
      dm[mt] += 64.0f * CL;
    }

    __builtin_amdgcn_s_waitcnt(0xC07F);  // lgkmcnt(0): own-wave P writes visible

    bf16x8 pf0 = *(const bf16x8*)&Ps[w][l15][q4 * 8];
    bf16x8 pf1 = *(const bf16x8*)&Ps[w][l15][32 + q4 * 8];
    lsum = __builtin_amdgcn_mfma_f32_16x16x32_bf16(pf0, ones, lsum, 0, 0, 0);
    lsum = __builtin_amdgcn_mfma_f32_16x16x32_bf16(pf1, ones, lsum, 0, 0, 0);
#pragma unroll
    for (int dt = 0; dt < 4; ++dt) {
      int row = dt * 16 + l15;
      int s0 = q4 ^ (row & 7);
      int s1 = (4 + q4) ^ (row & 7);
      bf16x8 vf0 = *(const bf16x8*)&Vs[cur][row * 64 + s0 * 8];
      bf16x8 vf1 = *(const bf16x8*)&Vs[cur][row * 64 + s1 * 8];
      o_acc[dt] = __builtin_amdgcn_mfma_f32_16x16x32_bf16(pf0, vf0, o_acc[dt], 0, 0, 0);
      o_acc[dt] = __builtin_amdgcn_mfma_f32_16x16x32_bf16(pf1, vf1, o_acc[dt], 0, 0, 0);
    }
  }

  floatx4 inv;
#pragma unroll
  for (int r = 0; r < 4; ++r) inv[r] = 1.0f / lsum[r];
#pragma unroll
  for (int dt = 0; dt < 4; ++dt)
#pragma unroll
    for (int r = 0; r < 4; ++r) {
      int i = i0 + w * 16 + q4 * 4 + r;
      AO[((size_t)(b * 2048 + i)) * 1024 + h * 64 + dt * 16 + l15] =
          (bf16_t)(o_acc[dt][r] * inv[r]);
    }
}

// ---------------- launch ----------------
extern "C" void kernel_launch(void* const* d_in, const int* in_sizes, int n_in,
                              void* d_out, int out_size, void* d_ws, size_t ws_size,
                              hipStream_t stream) {
  const float* x  = (const float*)d_in[0];
  const float* Wq = (const float*)d_in[1];
  const float* bq = (const float*)d_in[2];
  const float* Wk = (const float*)d_in[3];
  const float* bk = (const float*)d_in[4];
  const float* Wv = (const float*)d_in[5];
  const float* bv = (const float*)d_in[6];
  const float* Wo = (const float*)d_in[7];
  const float* bo = (const float*)d_in[8];

  char* ws = (char*)d_ws;                      // needs >= 48 MB
  bf16_t* xb  = (bf16_t*)(ws);                 //  8 MB
  bf16_t* wqb = (bf16_t*)(ws + (8u  << 20));   //  2 MB (wq,wk,wv,wo contiguous)
  bf16_t* wob = (bf16_t*)(ws + (14u << 20));
  bf16_t* Qb  = (bf16_t*)(ws + (16u << 20));   //  8 MB  [b,t,h,d]
  bf16_t* Kb  = (bf16_t*)(ws + (24u << 20));   //  8 MB  [b,t,h,d]
  bf16_t* Vtb = (bf16_t*)(ws + (32u << 20));   //  8 MB  [b,h*d,t]
  bf16_t* AOb = (bf16_t*)(ws + (40u << 20));   //  8 MB  [b,t,h,d]

  castall<<<8192, 256, 0, stream>>>(x, Wq, Wk, Wv, Wo, xb, wqb);

  // QKV over stacked W [3072x1024]: 256 blocks (16m x 16n), 512 thr, 1/CU
  gemm_qkv<<<256, 512, 0, stream>>>(
      xb, wqb, bq, bk, bv, Qb, Kb, Vtb);

  attn_kernel<<<1024, 256, 0, stream>>>(Qb, Kb, Vtb, AOb);

  // out: 256 blocks (32 m x 8 n) x 512 threads, dbuf, 2 blocks/CU
  gemm_out<<<256, 512, 0, stream>>>(AOb, wob, bo, (float*)d_out);
}

// Round 9
// 148.273 us; speedup vs baseline: 1.0861x; 1.0019x over previous
//
#include <hip/hip_runtime.h>
#include <hip/hip_bf16.h>
#include <math.h>

// B=2, T=2048, D=1024, H=16, hd=64, ALPHA=1 (decay = -(i-j))
// Pipeline: fused cast f32->bf16
//  -> QKV NT GEMM over stacked W [3072x1024]: 256x96 tile, 4 waves of 64x96
//     (wave-level reuse A/B: LDS bytes/FLOP x0.86 vs r4's 64x64 waves; five
//     schedule variants all hit ~650 TF -> testing LDS-traffic as the wall),
//     256 thr, single-buf 44 KB LDS, grid 512 = exactly 2 blocks/CU.
//  -> windowed flash attn (j-tiles {qb-1,qb}; decay kills distance>64)
//  -> out NT GEMM (128x128 dbuf).
// NOTE: ~86us of dur_us is two 268MB harness poison-fills (43us each);
// controllable budget ~62us; qkv 2-phase/8-phase/counted all ~40us.

typedef __bf16 bf16_t;
typedef bf16_t bf16x8 __attribute__((ext_vector_type(8)));
typedef bf16_t bf16x4 __attribute__((ext_vector_type(4)));
typedef float  floatx4 __attribute__((ext_vector_type(4)));

#define LOG2E 1.44269504088896f

#if __has_builtin(__builtin_amdgcn_exp2f)
#define EXP2(x) __builtin_amdgcn_exp2f(x)
#else
#define EXP2(x) exp2f(x)
#endif

__device__ __forceinline__ void async16(const bf16_t* g, bf16_t* l) {
  __builtin_amdgcn_global_load_lds(
      (const __attribute__((address_space(1))) unsigned int*)g,
      (__attribute__((address_space(3))) unsigned int*)l, 16, 0, 0);
}

// pack two f32 into bf16x2 by truncation (1 v_perm_b32); P>=0 -> rel err <= 2^-8
__device__ __forceinline__ unsigned pack_bf16_trunc(float lo, float hi) {
  return __builtin_amdgcn_perm(__builtin_bit_cast(unsigned, hi),
                               __builtin_bit_cast(unsigned, lo), 0x07060302u);
}

// ---------------- fused cast kernel ----------------
__global__ void castall(const float* __restrict__ x,
                        const float* __restrict__ wq, const float* __restrict__ wk,
                        const float* __restrict__ wv, const float* __restrict__ wo,
                        bf16_t* __restrict__ xb, bf16_t* __restrict__ wdst) {
  int i = blockIdx.x * blockDim.x + threadIdx.x;  // 0 .. 2097151
  const float* src;
  bf16_t* dst;
  if (i < 1048576) {
    src = x + (size_t)i * 4;
    dst = xb + (size_t)i * 4;
  } else {
    int i2 = i - 1048576;
    int wsel = i2 >> 18;
    int off = i2 & 262143;
    const float* wsrc = (wsel == 0) ? wq : (wsel == 1) ? wk : (wsel == 2) ? wv : wo;
    src = wsrc + (size_t)off * 4;
    dst = wdst + (size_t)i2 * 4;
  }
  const float4 f = *(const float4*)src;
  bf16x4 o;
  o[0] = (bf16_t)f.x; o[1] = (bf16_t)f.y; o[2] = (bf16_t)f.z; o[3] = (bf16_t)f.w;
  *(bf16x4*)dst = o;
}

// ---------------- QKV NT GEMM: C[4096x3072] = A[4096x1024].Wst^T ----------------
// 256x96 tile, BK=64, 256 thr (4 waves stacked in m: wave = 64 rows x 96 cols,
// 4x6 fragments), single-buffer LDS, grid 512 (16m x 32n) = 2 blocks/CU exact.
#define BK 64

__global__ __launch_bounds__(256, 2)
void gemm_qkv(const bf16_t* __restrict__ A, const bf16_t* __restrict__ Wst,
              const float* __restrict__ b0, const float* __restrict__ b1,
              const float* __restrict__ b2,
              bf16_t* __restrict__ O0, bf16_t* __restrict__ O1,
              bf16_t* __restrict__ O2)
{
  __shared__ __align__(16) bf16_t As[256 * BK];   // 32 KB
  __shared__ __align__(16) bf16_t Bs[96 * BK];    // 12 KB
  const int t = threadIdx.x, w = t >> 6, lane = t & 63;
  const int l15 = lane & 15, q4 = lane >> 4;
  // XCD-bijective swizzle (512 = 8 * 64)
  const int orig = blockIdx.x;
  const int wgid = (orig & 7) * 64 + (orig >> 3);
  const int mb = wgid >> 5, nb = wgid & 31;       // 16 m x 32 n
  const int m0 = mb * 256, n0 = nb * 96;
  const int wm = w * 64;                          // 4 waves stacked in m

  floatx4 acc[4][6];
#pragma unroll
  for (int mi = 0; mi < 4; ++mi)
#pragma unroll
    for (int ni = 0; ni < 6; ++ni) acc[mi][ni] = (floatx4){0.f, 0.f, 0.f, 0.f};

  // staging: A 2048 chunks (8/thread), B 768 chunks (3/thread); phys slot
  // chunk&7 holds global seg (chunk&7)^(row&7) (XOR swizzle, row stride 128 B)
  for (int k0 = 0; k0 < 1024; k0 += BK) {
#pragma unroll
    for (int c = 0; c < 8; ++c) {
      int chunk = t + c * 256;              // 0..2047
      int row = chunk >> 3;
      int g = (chunk & 7) ^ (row & 7);
      async16(A + (size_t)(m0 + row) * 1024 + k0 + g * 8, &As[chunk * 8]);
    }
#pragma unroll
    for (int c = 0; c < 3; ++c) {
      int chunk = t + c * 256;              // 0..767
      int row = chunk >> 3;
      int g = (chunk & 7) ^ (row & 7);
      async16(Wst + (size_t)(n0 + row) * 1024 + k0 + g * 8, &Bs[chunk * 8]);
    }
    __syncthreads();

#pragma unroll
    for (int kk = 0; kk < 2; ++kk) {
      bf16x8 af[4], bfr[6];
#pragma unroll
      for (int i = 0; i < 4; ++i) {
        int ra = wm + i * 16 + l15;
        int pa = (kk * 4 + q4) ^ (ra & 7);
        af[i] = *(const bf16x8*)&As[ra * BK + pa * 8];
      }
#pragma unroll
      for (int j = 0; j < 6; ++j) {
        int rb = j * 16 + l15;
        int pb = (kk * 4 + q4) ^ (rb & 7);
        bfr[j] = *(const bf16x8*)&Bs[rb * BK + pb * 8];
      }
#pragma unroll
      for (int mi = 0; mi < 4; ++mi)
#pragma unroll
        for (int ni = 0; ni < 6; ++ni)
          acc[mi][ni] = __builtin_amdgcn_mfma_f32_16x16x32_bf16(
              af[mi], bfr[ni], acc[mi][ni], 0, 0, 0);
    }
    __syncthreads();
  }

  // epilogue; C/D layout: col = lane&15, row = (lane>>4)*4 + reg.
  // 96-wide tiles straddle the 1024-col Q/K/V boundaries; each 16-col
  // fragment is 16-aligned (1024 % 16 == 0) -> per-fragment lane-uniform cmat.
#pragma unroll
  for (int mi = 0; mi < 4; ++mi) {
    const int rowg = m0 + wm + mi * 16 + q4 * 4;
#pragma unroll
    for (int ni = 0; ni < 6; ++ni) {
      const int col = n0 + ni * 16 + l15;
      const int cmat = col >> 10, lcol = col & 1023;
      const float* bp = (cmat == 0) ? b0 : (cmat == 1) ? b1 : b2;
      const float bv = bp[lcol];
      if (cmat == 2) {
        // V transposed: Vt[b][d][t]; lane holds 4 consecutive t -> 8B store
        int bb = rowg >> 11, tt = rowg & 2047;
        bf16x4 pk;
#pragma unroll
        for (int r = 0; r < 4; ++r) pk[r] = (bf16_t)(acc[mi][ni][r] + bv);
        *(bf16x4*)(O2 + (size_t)(bb * 1024 + lcol) * 2048 + tt) = pk;
      } else {
        bf16_t* Om = cmat ? O1 : O0;
#pragma unroll
        for (int r = 0; r < 4; ++r)
          Om[(size_t)(rowg + r) * 1024 + lcol] = (bf16_t)(acc[mi][ni][r] + bv);
      }
    }
  }
}

// ---------------- out NT GEMM: 128x128 tile, dbuf, 2 blocks/CU (f32 out) ----------------
__global__ __launch_bounds__(512, 2)
void gemm_out(const bf16_t* __restrict__ A, const bf16_t* __restrict__ Wm,
              const float* __restrict__ bias, float* __restrict__ OF)
{
  __shared__ __align__(16) bf16_t As[2][128 * BK];   // 32 KB
  __shared__ __align__(16) bf16_t Bs[2][128 * BK];   // 32 KB
  const int t = threadIdx.x, w = t >> 6, lane = t & 63;
  const int l15 = lane & 15, q4 = lane >> 4;
  const int orig = blockIdx.x;
  const int wgid = (orig & 7) * 32 + (orig >> 3);    // XCD-bijective swizzle
  const int mb = wgid >> 3, nbk = wgid & 7;          // 32 m x 8 n
  const int m0 = mb * 128, n0 = nbk * 128;
  const int wm = (w >> 2) * 64, wn = (w & 3) * 32;   // 2x4 wave grid over 128x128

  floatx4 acc[4][2];
#pragma unroll
  for (int mi = 0; mi < 4; ++mi)
#pragma unroll
    for (int ni = 0; ni < 2; ++ni) acc[mi][ni] = (floatx4){0.f, 0.f, 0.f, 0.f};

  auto stage = [&](int buf, int k0) {
#pragma unroll
    for (int c = 0; c < 2; ++c) {
      int chunk = t + c * 512;                 // 0..1023
      int row = chunk >> 3;
      int g = (chunk & 7) ^ (row & 7);
      async16(A  + (size_t)(m0 + row) * 1024 + k0 + g * 8, &As[buf][chunk * 8]);
      async16(Wm + (size_t)(n0 + row) * 1024 + k0 + g * 8, &Bs[buf][chunk * 8]);
    }
  };

  stage(0, 0);
  __syncthreads();
  for (int it = 0; it < 16; ++it) {
    const int cur = it & 1;
    if (it + 1 < 16) stage(cur ^ 1, (it + 1) * BK);

#pragma unroll
    for (int kk = 0; kk < 2; ++kk) {
      bf16x8 af[4], bfr[2];
#pragma unroll
      for (int i = 0; i < 4; ++i) {
        int ra = wm + i * 16 + l15;
        int pa = (kk * 4 + q4) ^ (ra & 7);
        af[i] = *(const bf16x8*)&As[cur][ra * BK + pa * 8];
      }
#pragma unroll
      for (int i = 0; i < 2; ++i) {
        int rb = wn + i * 16 + l15;
        int pb = (kk * 4 + q4) ^ (rb & 7);
        bfr[i] = *(const bf16x8*)&Bs[cur][rb * BK + pb * 8];
      }
#pragma unroll
      for (int mi = 0; mi < 4; ++mi)
#pragma unroll
        for (int ni = 0; ni < 2; ++ni)
          acc[mi][ni] = __builtin_amdgcn_mfma_f32_16x16x32_bf16(
              af[mi], bfr[ni], acc[mi][ni], 0, 0, 0);
    }
    __syncthreads();
  }

#pragma unroll
  for (int mi = 0; mi < 4; ++mi)
#pragma unroll
    for (int ni = 0; ni < 2; ++ni) {
      const int col = n0 + wn + ni * 16 + l15;
      const float bv = bias[col];
#pragma unroll
      for (int r = 0; r < 4; ++r) {
        int row = m0 + wm + mi * 16 + q4 * 4 + r;
        OF[(size_t)row * 1024 + col] = acc[mi][ni][r] + bv;
      }
    }
}

// ---------------- windowed flash attention: j-tiles {qb-1, qb} only ----------------
// decay e^{-(i-j)} makes keys at distance >64 weigh < e^{-58}: below f32 ulp.
__global__ __launch_bounds__(256, 3)
void attn_kernel(const bf16_t* __restrict__ Qb, const bf16_t* __restrict__ Kb,
                 const bf16_t* __restrict__ Vt, bf16_t* __restrict__ AO)
{
  __shared__ __align__(16) bf16_t Ks[2][64 * 64];
  __shared__ __align__(16) bf16_t Vs[2][64 * 64];
  __shared__ __align__(16) bf16_t Ps[4][16][72];

  const int t = threadIdx.x, w = t >> 6, lane = t & 63;
  const int l15 = lane & 15, q4 = lane >> 4;
  const int bh = blockIdx.x & 31, qb = blockIdx.x >> 5;
  const int b = bh >> 4, h = bh & 15;
  const int i0 = qb * 64;
  const int jstart = (qb > 0) ? (qb - 1) : 0;
  const int nIter = qb - jstart + 1;      // 1 (qb==0) or 2

  const float C1 = 0.125f * LOG2E;        // (1/sqrt(64)) * log2e
  const float CL = LOG2E;
  const float Er[4] = {1.0f, 2.71828182846f, 7.38905609893f, 20.0855369232f};

  const bf16_t* qp = Qb + ((size_t)(b * 2048 + i0 + w * 16 + l15)) * 1024 + h * 64 + q4 * 8;
  const bf16x8 qf0 = *(const bf16x8*)qp;
  const bf16x8 qf1 = *(const bf16x8*)(qp + 32);

  floatx4 o_acc[4], lsum;
  lsum = (floatx4){0.f, 0.f, 0.f, 0.f};
#pragma unroll
  for (int dt = 0; dt < 4; ++dt) o_acc[dt] = (floatx4){0.f, 0.f, 0.f, 0.f};
  bf16x8 ones;
#pragma unroll
  for (int e = 0; e < 8; ++e) ones[e] = (bf16_t)1.0f;

  float dm[4];
#pragma unroll
  for (int mt = 0; mt < 4; ++mt)
    dm[mt] = (float)(jstart * 64 + mt * 16 + q4 * 4 - w * 16 - l15 - i0) * CL;
  const int relMask = w * 16 + l15;

  const int chA = w * 128 + lane, chB = chA + 64;
  const int rA = chA >> 3, rB = chB >> 3;
  const int sA = (chA & 7) ^ (rA & 7), sB = (chB & 7) ^ (rB & 7);
  const bf16_t* kpA = Kb + ((size_t)(b * 2048 + jstart * 64 + rA)) * 1024 + h * 64 + sA * 8;
  const bf16_t* kpB = Kb + ((size_t)(b * 2048 + jstart * 64 + rB)) * 1024 + h * 64 + sB * 8;
  const bf16_t* vpA = Vt + ((size_t)(b * 1024 + h * 64 + rA)) * 2048 + jstart * 64 + sA * 8;
  const bf16_t* vpB = Vt + ((size_t)(b * 1024 + h * 64 + rB)) * 2048 + jstart * 64 + sB * 8;

  auto stage = [&](int buf) {
    async16(kpA, &Ks[buf][chA * 8]);
    async16(kpB, &Ks[buf][chB * 8]);
    async16(vpA, &Vs[buf][chA * 8]);
    async16(vpB, &Vs[buf][chB * 8]);
    kpA += 65536; kpB += 65536;
    vpA += 64;    vpB += 64;
  };

  stage(0);
  for (int it = 0; it < nIter; ++it) {
    __syncthreads();
    if (it + 1 < nIter) stage(1);
    const int cur = it;

    const bool diag = (it == nIter - 1);
#pragma unroll
    for (int mt = 0; mt < 4; ++mt) {
      int row = mt * 16 + l15;
      int s0 = q4 ^ (row & 7);
      int s1 = (4 + q4) ^ (row & 7);
      bf16x8 kf0 = *(const bf16x8*)&Ks[cur][row * 64 + s0 * 8];
      bf16x8 kf1 = *(const bf16x8*)&Ks[cur][row * 64 + s1 * 8];
      floatx4 s4 = __builtin_amdgcn_mfma_f32_16x16x32_bf16(kf0, qf0,
                       (floatx4){0.f, 0.f, 0.f, 0.f}, 0, 0, 0);
      s4 = __builtin_amdgcn_mfma_f32_16x16x32_bf16(kf1, qf1, s4, 0, 0, 0);

      float p[4];
#pragma unroll
      for (int r = 0; r < 4; ++r) {
        float v = EXP2(fmaf(s4[r], C1, dm[mt])) * Er[r];
        if (diag && (mt * 16 + q4 * 4 + r) > relMask) v = 0.f;
        p[r] = v;
      }
      uint2 pk2;
      pk2.x = pack_bf16_trunc(p[0], p[1]);
      pk2.y = pack_bf16_trunc(p[2], p[3]);
      *(uint2*)&Ps[w][l15][mt * 16 + q4 * 4] = pk2;
      dm[mt] += 64.0f * CL;
    }

    __builtin_amdgcn_s_waitcnt(0xC07F);  // lgkmcnt(0): own-wave P writes visible

    bf16x8 pf0 = *(const bf16x8*)&Ps[w][l15][q4 * 8];
    bf16x8 pf1 = *(const bf16x8*)&Ps[w][l15][32 + q4 * 8];
    lsum = __builtin_amdgcn_mfma_f32_16x16x32_bf16(pf0, ones, lsum, 0, 0, 0);
    lsum = __builtin_amdgcn_mfma_f32_16x16x32_bf16(pf1, ones, lsum, 0, 0, 0);
#pragma unroll
    for (int dt = 0; dt < 4; ++dt) {
      int row = dt * 16 + l15;
      int s0 = q4 ^ (row & 7);
      int s1 = (4 + q4) ^ (row & 7);
      bf16x8 vf0 = *(const bf16x8*)&Vs[cur][row * 64 + s0 * 8];
      bf16x8 vf1 = *(const bf16x8*)&Vs[cur][row * 64 + s1 * 8];
      o_acc[dt] = __builtin_amdgcn_mfma_f32_16x16x32_bf16(pf0, vf0, o_acc[dt], 0, 0, 0);
      o_acc[dt] = __builtin_amdgcn_mfma_f32_16x16x32_bf16(pf1, vf1, o_acc[dt], 0, 0, 0);
    }
  }

  floatx4 inv;
#pragma unroll
  for (int r = 0; r < 4; ++r) inv[r] = 1.0f / lsum[r];
#pragma unroll
  for (int dt = 0; dt < 4; ++dt)
#pragma unroll
    for (int r = 0; r < 4; ++r) {
      int i = i0 + w * 16 + q4 * 4 + r;
      AO[((size_t)(b * 2048 + i)) * 1024 + h * 64 + dt * 16 + l15] =
          (bf16_t)(o_acc[dt][r] * inv[r]);
    }
}

// ---------------- launch ----------------
extern "C" void kernel_launch(void* const* d_in, const int* in_sizes, int n_in,
                              void* d_out, int out_size, void* d_ws, size_t ws_size,
                              hipStream_t stream) {
  const float* x  = (const float*)d_in[0];
  const float* Wq = (const float*)d_in[1];
  const float* bq = (const float*)d_in[2];
  const float* Wk = (const float*)d_in[3];
  const float* bk = (const float*)d_in[4];
  const float* Wv = (const float*)d_in[5];
  const float* bv = (const float*)d_in[6];
  const float* Wo = (const float*)d_in[7];
  const float* bo = (const float*)d_in[8];

  char* ws = (char*)d_ws;                      // needs >= 48 MB
  bf16_t* xb  = (bf16_t*)(ws);                 //  8 MB
  bf16_t* wqb = (bf16_t*)(ws + (8u  << 20));   //  2 MB (wq,wk,wv,wo contiguous)
  bf16_t* wob = (bf16_t*)(ws + (14u << 20));
  bf16_t* Qb  = (bf16_t*)(ws + (16u << 20));   //  8 MB  [b,t,h,d]
  bf16_t* Kb  = (bf16_t*)(ws + (24u << 20));   //  8 MB  [b,t,h,d]
  bf16_t* Vtb = (bf16_t*)(ws + (32u << 20));   //  8 MB  [b,h*d,t]
  bf16_t* AOb = (bf16_t*)(ws + (40u << 20));   //  8 MB  [b,t,h,d]

  castall<<<8192, 256, 0, stream>>>(x, Wq, Wk, Wv, Wo, xb, wqb);

  // QKV over stacked W [3072x1024]: 512 blocks (16m x 32n), 256 thr,
  // 2 blocks/CU exact, all co-resident.
  gemm_qkv<<<512, 256, 0, stream>>>(
      xb, wqb, bq, bk, bv, Qb, Kb, Vtb);

  attn_kernel<<<1024, 256, 0, stream>>>(Qb, Kb, Vtb, AOb);

  // out: 256 blocks (32 m x 8 n) x 512 threads, dbuf, 2 blocks/CU
  gemm_out<<<256, 512, 0, stream>>>(AOb, wob, bo, (float*)d_out);
}